// Round 6
// baseline (121.032 us; speedup 1.0000x reference)
//
#include <hip/hip_runtime.h>
#include <math.h>

#define NBATCH 4
#define NV 9
#define DM 64
#define DS 16
// H = W = 32, image = 1024 pixels

__device__ __forceinline__ float softplus_f(float x) {
    return (x > 20.f) ? x : log1pf(__expf(x));
}

// ---------------------------------------------------------------------------
// Kernel 1: fused circular 3x3 convs, ci split 4-ways inside the block.
// Grid: 4(b) * 96(co) * 4(ht) = 1536 blocks, 256 threads.
//   wave w (= tid>>6) handles ci in [w*16, w*16+16)  (wave-uniform chunk)
//   pxt = tid & 63 -> 4 consecutive pixels of one row in the 8-row tile.
// Partials reduced through LDS; epilogue fused (bias+softplus for delta).
// ---------------------------------------------------------------------------
__global__ __launch_bounds__(256) void conv_kernel(
    const float* __restrict__ u, const float* __restrict__ wd,
    const float* __restrict__ bd, const float* __restrict__ wb,
    const float* __restrict__ wc, const float* __restrict__ dtp,
    float* __restrict__ delta_out, float* __restrict__ Bv_out,
    float* __restrict__ Cv_out)
{
    int bx = blockIdx.x;
    int ht = bx & 3;
    int co = (bx >> 2) % 96;
    int b  = bx / 384;
    int tid = threadIdx.x;
    int chunk = __builtin_amdgcn_readfirstlane(tid >> 6);  // wave-uniform -> SGPR
    int pxt = tid & 63;
    int row = ht * 8 + (pxt >> 3);
    int w0  = (pxt & 7) << 2;

    const float* wbase = (co < 64) ? (wd + (size_t)co * 576)
                       : (co < 80) ? (wb + (size_t)(co - 64) * 576)
                                   : (wc + (size_t)(co - 80) * 576);

    int hm = (row + 31) & 31, hp = (row + 1) & 31;
    int wl = (w0 + 31) & 31;   // col w0-1 (wrapped)
    int wr = (w0 + 4) & 31;    // col w0+4 (wrapped)
    const float* ub = u + (size_t)b * 65536 + (size_t)(chunk << 4) * 1024;
    const float* wq0 = wbase + (size_t)(chunk << 4) * 9;

    float a0 = 0.f, a1 = 0.f, a2 = 0.f, a3 = 0.f;
    #pragma unroll 4
    for (int j = 0; j < 16; ++j) {
        const float* base = ub + j * 1024;
        const float* wq = wq0 + j * 9;
        #pragma unroll
        for (int r = 0; r < 3; ++r) {
            int rr = (r == 0) ? hm : (r == 1) ? row : hp;
            const float* rp = base + rr * 32;
            float4 v = *(const float4*)(rp + w0);
            float L = rp[wl], R = rp[wr];
            float k0 = wq[r * 3 + 0], k1 = wq[r * 3 + 1], k2 = wq[r * 3 + 2];
            a0 = fmaf(k0, L,   fmaf(k1, v.x, fmaf(k2, v.y, a0)));
            a1 = fmaf(k0, v.x, fmaf(k1, v.y, fmaf(k2, v.z, a1)));
            a2 = fmaf(k0, v.y, fmaf(k1, v.z, fmaf(k2, v.w, a2)));
            a3 = fmaf(k0, v.z, fmaf(k1, v.w, fmaf(k2, R,   a3)));
        }
    }

    __shared__ float4 part[4][64];
    part[chunk][pxt] = make_float4(a0, a1, a2, a3);
    __syncthreads();

    if (tid < 64) {
        float4 p0 = part[0][tid], p1 = part[1][tid];
        float4 p2 = part[2][tid], p3 = part[3][tid];
        float s0 = p0.x + p1.x + p2.x + p3.x;
        float s1 = p0.y + p1.y + p2.y + p3.y;
        float s2 = p0.z + p1.z + p2.z + p3.z;
        float s3 = p0.w + p1.w + p2.w + p3.w;
        int prow = ht * 8 + (tid >> 3);
        int pw   = (tid & 7) << 2;
        int pix  = prow * 32 + pw;
        if (co < 64) {
            float bias = bd[co] + dtp[0];
            float4 o;
            o.x = softplus_f(s0 + bias);
            o.y = softplus_f(s1 + bias);
            o.z = softplus_f(s2 + bias);
            o.w = softplus_f(s3 + bias);
            *(float4*)(delta_out + (((size_t)b * 64 + co) << 10) + pix) = o;
        } else if (co < 80) {
            *(float4*)(Bv_out + (((size_t)b * 16 + (co - 64)) << 10) + pix) =
                make_float4(s0, s1, s2, s3);
        } else {
            *(float4*)(Cv_out + (((size_t)b * 16 + (co - 80)) << 10) + pix) =
                make_float4(s0, s1, s2, s3);
        }
    }
}

// ---------------------------------------------------------------------------
// Kernel 2: state update + y reduction. One thread per (b, i, c, pixel).
// Grid: 4(b)*9(i)*64(c)*4(t) = 9216 blocks, 256 threads -> 36864 waves.
// Full unroll over n; per-thread transcendentals (VALU is ~10% busy, free);
// REGULAR stores (nt stores measured ~1.5x slower end-to-end, R4/R5).
// ---------------------------------------------------------------------------
__global__ __launch_bounds__(256) void scan_kernel(
    const float* __restrict__ u, const float* __restrict__ s_prev,
    const float* __restrict__ logA, const float* __restrict__ Dp,
    const float* __restrict__ delta_in, const float* __restrict__ Bv,
    const float* __restrict__ Cv,
    float* __restrict__ y_out, float* __restrict__ s_next)
{
    int bx = blockIdx.x;
    int t  = bx & 3;
    int c  = (bx >> 2) & 63;
    int bi = bx >> 8;           // b*9 + i
    int i  = bi % 9;
    int b  = bi / 9;

    int tid = threadIdx.x;
    int pix = t * 256 + tid;
    int h = pix >> 5, w = pix & 31;

    int vx = i / 3 - 1;
    int vy = i % 3 - 1;
    int hh = (h + vy + 32) & 31;
    int ww = (w + vx + 32) & 31;

    float uv = u[(((size_t)b * 64 + c) << 10) + pix];
    float dv = delta_in[(((size_t)b * 64 + c) << 10) + pix];
    float y  = uv * Dp[c];

    size_t chan = ((size_t)bi * 64 + c) * 16;
    const float* sp  = s_prev + (chan << 10) + hh * 32 + ww;
    float*       sn  = s_next + (chan << 10) + pix;
    const float* bvp = Bv + (((size_t)b * 16) << 10) + pix;
    const float* cvp = Cv + (((size_t)b * 16) << 10) + pix;
    const float* la  = logA + c * 16;

    #pragma unroll
    for (int n = 0; n < 16; ++n) {
        float A    = -__expf(la[n]);                       // A = -exp(log_A_real)
        float ab   = __expf(dv * A);                       // A_bar
        float coef = (ab - 1.0f) * __builtin_amdgcn_rcpf(A);
        float bu   = coef * bvp[(size_t)n << 10] * uv;     // B_bar * u
        float s    = sp[(size_t)n << 10];
        float v    = fmaf(ab, s, bu);
        sn[(size_t)n << 10] = v;
        y = fmaf(v, cvp[(size_t)n << 10], y);
    }
    y_out[((size_t)bi * 64 + c) * 1024 + pix] = y;
}

extern "C" void kernel_launch(void* const* d_in, const int* in_sizes, int n_in,
                              void* d_out, int out_size, void* d_ws, size_t ws_size,
                              hipStream_t stream) {
    const float* u      = (const float*)d_in[0];
    const float* s_prev = (const float*)d_in[1];
    const float* wd     = (const float*)d_in[2];
    const float* bd     = (const float*)d_in[3];
    const float* wb     = (const float*)d_in[4];
    const float* wc     = (const float*)d_in[5];
    const float* logA   = (const float*)d_in[6];
    const float* Dp     = (const float*)d_in[7];
    const float* dtp    = (const float*)d_in[8];

    float* ws    = (float*)d_ws;
    float* delta = ws;                 // 4*64*1024   = 262144 floats
    float* Bv    = ws + 262144;        // 4*16*1024   =  65536 floats
    float* Cv    = ws + 327680;        // 4*16*1024   =  65536 floats

    float* y_out  = (float*)d_out;                            // 4*9*64*1024
    float* s_next = y_out + (size_t)NBATCH * NV * DM * 1024;  // 4*9*64*16*1024

    conv_kernel<<<dim3(4 * 96 * 4), dim3(256), 0, stream>>>(
        u, wd, bd, wb, wc, dtp, delta, Bv, Cv);
    scan_kernel<<<dim3(4 * 9 * 64 * 4), dim3(256), 0, stream>>>(
        u, s_prev, logA, Dp, delta, Bv, Cv, y_out, s_next);
}

// Round 7
// 102.047 us; speedup vs baseline: 1.1860x; 1.1860x over previous
//
#include <hip/hip_runtime.h>
#include <math.h>

#define NBATCH 4
#define NV 9
#define DM 64
#define DS 16
// H = W = 32, image = 1024 pixels

typedef float f32x4 __attribute__((ext_vector_type(4)));

__device__ __forceinline__ float softplus_f(float x) {
    return (x > 20.f) ? x : log1pf(__expf(x));
}

// ---------------------------------------------------------------------------
// Kernel 1: fused circular 3x3 convs, ci split 4-ways inside the block.
// Grid: 4(b) * 96(co) * 4(ht) = 1536 blocks, 256 threads.  (~9 us measured)
// ---------------------------------------------------------------------------
__global__ __launch_bounds__(256) void conv_kernel(
    const float* __restrict__ u, const float* __restrict__ wd,
    const float* __restrict__ bd, const float* __restrict__ wb,
    const float* __restrict__ wc, const float* __restrict__ dtp,
    float* __restrict__ delta_out, float* __restrict__ Bv_out,
    float* __restrict__ Cv_out)
{
    int bx = blockIdx.x;
    int ht = bx & 3;
    int co = (bx >> 2) % 96;
    int b  = bx / 384;
    int tid = threadIdx.x;
    int chunk = __builtin_amdgcn_readfirstlane(tid >> 6);  // wave-uniform -> SGPR
    int pxt = tid & 63;
    int row = ht * 8 + (pxt >> 3);
    int w0  = (pxt & 7) << 2;

    const float* wbase = (co < 64) ? (wd + (size_t)co * 576)
                       : (co < 80) ? (wb + (size_t)(co - 64) * 576)
                                   : (wc + (size_t)(co - 80) * 576);

    int hm = (row + 31) & 31, hp = (row + 1) & 31;
    int wl = (w0 + 31) & 31;   // col w0-1 (wrapped)
    int wr = (w0 + 4) & 31;    // col w0+4 (wrapped)
    const float* ub = u + (size_t)b * 65536 + (size_t)(chunk << 4) * 1024;
    const float* wq0 = wbase + (size_t)(chunk << 4) * 9;

    float a0 = 0.f, a1 = 0.f, a2 = 0.f, a3 = 0.f;
    #pragma unroll 4
    for (int j = 0; j < 16; ++j) {
        const float* base = ub + j * 1024;
        const float* wq = wq0 + j * 9;
        #pragma unroll
        for (int r = 0; r < 3; ++r) {
            int rr = (r == 0) ? hm : (r == 1) ? row : hp;
            const float* rp = base + rr * 32;
            float4 v = *(const float4*)(rp + w0);
            float L = rp[wl], R = rp[wr];
            float k0 = wq[r * 3 + 0], k1 = wq[r * 3 + 1], k2 = wq[r * 3 + 2];
            a0 = fmaf(k0, L,   fmaf(k1, v.x, fmaf(k2, v.y, a0)));
            a1 = fmaf(k0, v.x, fmaf(k1, v.y, fmaf(k2, v.z, a1)));
            a2 = fmaf(k0, v.y, fmaf(k1, v.z, fmaf(k2, v.w, a2)));
            a3 = fmaf(k0, v.z, fmaf(k1, v.w, fmaf(k2, R,   a3)));
        }
    }

    __shared__ float4 part[4][64];
    part[chunk][pxt] = make_float4(a0, a1, a2, a3);
    __syncthreads();

    if (tid < 64) {
        float4 p0 = part[0][tid], p1 = part[1][tid];
        float4 p2 = part[2][tid], p3 = part[3][tid];
        float s0 = p0.x + p1.x + p2.x + p3.x;
        float s1 = p0.y + p1.y + p2.y + p3.y;
        float s2 = p0.z + p1.z + p2.z + p3.z;
        float s3 = p0.w + p1.w + p2.w + p3.w;
        int prow = ht * 8 + (tid >> 3);
        int pw   = (tid & 7) << 2;
        int pix  = prow * 32 + pw;
        if (co < 64) {
            float bias = bd[co] + dtp[0];
            float4 o;
            o.x = softplus_f(s0 + bias);
            o.y = softplus_f(s1 + bias);
            o.z = softplus_f(s2 + bias);
            o.w = softplus_f(s3 + bias);
            *(float4*)(delta_out + (((size_t)b * 64 + co) << 10) + pix) = o;
        } else if (co < 80) {
            *(float4*)(Bv_out + (((size_t)b * 16 + (co - 64)) << 10) + pix) =
                make_float4(s0, s1, s2, s3);
        } else {
            *(float4*)(Cv_out + (((size_t)b * 16 + (co - 80)) << 10) + pix) =
                make_float4(s0, s1, s2, s3);
        }
    }
}

// ---------------------------------------------------------------------------
// Kernel 2: state update + y reduction. One thread per (b, i, c, 4 pixels).
// Grid: 4(b)*9(i)*64(c) = 2304 blocks, 256 threads.
// - ALL 16 s_prev float4 loads issued before any compute (sarr[16], static
//   indexing -> registers) to force deep MLP.
// - LDS table for (A, 1/A) (block-uniform c).
// - x-roll realigned with one __shfl in the 8-lane row group (block-uniform
//   branch, validated R3).
// - s_next / y_out stored non-temporally (measured -15us vs regular, R5/R6).
// ---------------------------------------------------------------------------
__global__ __launch_bounds__(256) void scan_kernel(
    const float* __restrict__ u, const float* __restrict__ s_prev,
    const float* __restrict__ logA, const float* __restrict__ Dp,
    const float* __restrict__ delta_in, const float* __restrict__ Bv,
    const float* __restrict__ Cv,
    float* __restrict__ y_out, float* __restrict__ s_next)
{
    int bx = blockIdx.x;
    int c  = bx & 63;
    int bi9 = bx >> 6;          // b*9 + i
    int i  = bi9 % 9;
    int b  = bi9 / 9;

    int tid = threadIdx.x;
    int pix0 = tid << 2;        // 4 consecutive pixels
    int h  = pix0 >> 5;
    int w0 = pix0 & 31;
    int vx = i / 3 - 1;
    int vy = i % 3 - 1;
    int hh = (h + vy + 32) & 31;

    int lane = tid & 63;
    int lnext = (lane & ~7) | ((lane + 1) & 7);
    int lprev = (lane & ~7) | ((lane + 7) & 7);

    __shared__ float sA[16], srA[16];
    if (tid < 16) {
        float A = -__expf(logA[c * 16 + tid]);
        sA[tid]  = A;
        srA[tid] = __builtin_amdgcn_rcpf(A);
    }
    __syncthreads();

    size_t ubase = (((size_t)b * 64 + c) << 10) + pix0;
    f32x4 u4 = *(const f32x4*)(u + ubase);
    f32x4 d4 = *(const f32x4*)(delta_in + ubase);
    float dk = Dp[c];
    f32x4 y4 = u4 * dk;

    size_t chan = ((size_t)bi9 * 64 + c) * 16;
    const float* sp_row = s_prev + (chan << 10) + hh * 32 + w0;
    float*       sn_px  = s_next + (chan << 10) + pix0;
    const float* bvp = Bv + (((size_t)b << 14)) + pix0;
    const float* cvp = Cv + (((size_t)b << 14)) + pix0;

    // Force all 16 independent s_prev loads in flight before compute.
    f32x4 sarr[16];
    #pragma unroll
    for (int n = 0; n < 16; ++n)
        sarr[n] = *(const f32x4*)(sp_row + ((size_t)n << 10));

    #pragma unroll
    for (int n = 0; n < 16; ++n) {
        float A  = sA[n];
        float rA = srA[n];

        f32x4 b4 = *(const f32x4*)(bvp + ((size_t)n << 10));
        f32x4 c4 = *(const f32x4*)(cvp + ((size_t)n << 10));

        f32x4 ab;
        ab.x = __expf(d4.x * A);
        ab.y = __expf(d4.y * A);
        ab.z = __expf(d4.z * A);
        ab.w = __expf(d4.w * A);

        f32x4 f = sarr[n];
        f32x4 s4;
        if (vx == 0) {
            s4 = f;
        } else if (vx > 0) {
            float t = __shfl(f.x, lnext);
            s4 = (f32x4){f.y, f.z, f.w, t};
        } else {
            float t = __shfl(f.w, lprev);
            s4 = (f32x4){t, f.x, f.y, f.z};
        }

        f32x4 bu = (ab - 1.0f) * rA * b4 * u4;
        f32x4 sn = ab * s4 + bu;
        __builtin_nontemporal_store(sn, (f32x4*)(sn_px + ((size_t)n << 10)));
        y4 += sn * c4;
    }
    __builtin_nontemporal_store(y4,
        (f32x4*)(y_out + (((size_t)bi9 * 64 + c) << 10) + pix0));
}

extern "C" void kernel_launch(void* const* d_in, const int* in_sizes, int n_in,
                              void* d_out, int out_size, void* d_ws, size_t ws_size,
                              hipStream_t stream) {
    const float* u      = (const float*)d_in[0];
    const float* s_prev = (const float*)d_in[1];
    const float* wd     = (const float*)d_in[2];
    const float* bd     = (const float*)d_in[3];
    const float* wb     = (const float*)d_in[4];
    const float* wc     = (const float*)d_in[5];
    const float* logA   = (const float*)d_in[6];
    const float* Dp     = (const float*)d_in[7];
    const float* dtp    = (const float*)d_in[8];

    float* ws    = (float*)d_ws;
    float* delta = ws;                 // 4*64*1024   = 262144 floats
    float* Bv    = ws + 262144;        // 4*16*1024   =  65536 floats
    float* Cv    = ws + 327680;        // 4*16*1024   =  65536 floats

    float* y_out  = (float*)d_out;                            // 4*9*64*1024
    float* s_next = y_out + (size_t)NBATCH * NV * DM * 1024;  // 4*9*64*16*1024

    conv_kernel<<<dim3(4 * 96 * 4), dim3(256), 0, stream>>>(
        u, wd, bd, wb, wc, dtp, delta, Bv, Cv);
    scan_kernel<<<dim3(4 * 9 * 64), dim3(256), 0, stream>>>(
        u, s_prev, logA, Dp, delta, Bv, Cv, y_out, s_next);
}